// Round 4
// baseline (102.817 us; speedup 1.0000x reference)
//
#include <hip/hip_runtime.h>

typedef __attribute__((ext_vector_type(8))) _Float16 half8;
typedef __attribute__((ext_vector_type(4))) float f32x4;

// ---- constants from the reference ----
#define COS_M 0.98006657784124163f
#define SIN_M 0.19866933079506122f
#define TH_C  (-0.98006657784124163f)
#define MM_C  0.039733866159012244f
#define S_OVER_TEMP (10.0f / 0.07f)

// monotone-in-c transform: c -> S*phi(c)/TEMP (loss invariant to stabilizer
// choice, so xform(rowmax * invn) works as the log-sum-exp stabilizer)
__device__ inline float xform(float c) {
  float s2 = fmaxf(1.0f - c * c, 0.0f);
  float sn = sqrtf(s2);
  float phi = c * COS_M - sn * SIN_M;
  float out = (c - TH_C > 0.0f) ? phi : (c - MM_C);
  return out * S_OVER_TEMP;
}

// grid barrier: agent-scope fences (wbl2/inv on gfx950) + device atomic counter.
// Counter zeroed by hipMemsetAsync before launch. Bounded spin: fail visibly,
// never hang the harness.
__device__ inline void gridbar(unsigned* cnt, unsigned target) {
  __syncthreads();  // drains this block's vmcnt (stores reached L2)
  if (threadIdx.x == 0) {
    __threadfence();  // release: buffer_wbl2 (flush this XCD's dirty L2 to L3)
    __hip_atomic_fetch_add(cnt, 1u, __ATOMIC_RELAXED, __HIP_MEMORY_SCOPE_AGENT);
    unsigned spins = 0;
    while (__hip_atomic_load(cnt, __ATOMIC_RELAXED, __HIP_MEMORY_SCOPE_AGENT) < target &&
           ++spins < 20000000u) {
      __builtin_amdgcn_s_sleep(8);
    }
  }
  __syncthreads();
  __threadfence();  // acquire (all threads): buffer_inv so fresh reads from L3
}

__global__ __launch_bounds__(256, 1) void k_fused(
    const float* __restrict__ feats, const int* __restrict__ labels,
    unsigned* __restrict__ cnts, float* __restrict__ partials,
    _Float16* __restrict__ cfn, _Float16* __restrict__ Gh,
    float* __restrict__ out) {
  // 103 KB LDS -> exactly 1 block/CU; grid 256 = #CUs -> co-resident by capacity
  __shared__ alignas(16) _Float16 la[128 * 200];  // stride 200: 2-way alias = free
  __shared__ alignas(16) _Float16 lb[128 * 200];
  __shared__ float cwS[8][4], cwM[8][4], cwE[8][4], cwP[8][4], cwC[8][4];
  __shared__ float r4[4];
  __shared__ int lastf;

  const int b = blockIdx.x, t = threadIdx.x;
  const int lane = t & 63, w = t >> 6;

  // ---- phase 0: L2-normalize rows b*8 .. b*8+7 of concat-view cf -> f16 ----
  {
    const int rr = t >> 5, g = t & 31;  // 32 threads per row
    const int r = b * 8 + rr;
    const float* src = feats + (size_t)((r & 1023) * 2 + (r >> 10)) * 192;
    float x[6];
    float ss = 0.f;
#pragma unroll
    for (int k = 0; k < 6; ++k) { x[k] = src[g + 32 * k]; ss += x[k] * x[k]; }
#pragma unroll
    for (int o = 16; o; o >>= 1) ss += __shfl_xor(ss, o);  // within 32-group
    const float inv = 1.0f / fmaxf(sqrtf(ss), 1e-12f);
    _Float16* dst = cfn + (size_t)r * 192;
#pragma unroll
    for (int k = 0; k < 6; ++k) dst[g + 32 * k] = (_Float16)(x[k] * inv);
  }
  gridbar(cnts + 0, 256);

  // ---- phase 1: G tile (128x128) = cfn * cfn^T via MFMA, f16 coalesced store
  {
    const int bm = b >> 4, bn = b & 15;  // 16x16 tile grid = 256 blocks exactly
    const uint4* srcA = (const uint4*)(cfn + (size_t)bm * 128 * 192);
    const uint4* srcB = (const uint4*)(cfn + (size_t)bn * 128 * 192);
    for (int idx = t; idx < 3072; idx += 256) {  // 128 rows * 24 uint4
      int r = idx / 24, c = idx - r * 24;
      *(uint4*)&la[r * 200 + c * 8] = srcA[idx];
      *(uint4*)&lb[r * 200 + c * 8] = srcB[idx];
    }
    __syncthreads();

    const int wr = w >> 1, wc = w & 1;  // 2x2 wave grid, 64x64 each
    const int lr = lane & 15, kg = lane >> 4;

    f32x4 acc[4][4];
#pragma unroll
    for (int m = 0; m < 4; ++m)
#pragma unroll
      for (int n = 0; n < 4; ++n) acc[m][n] = (f32x4){0.f, 0.f, 0.f, 0.f};

#pragma unroll
    for (int kc = 0; kc < 6; ++kc) {  // K = 192 = 6 * 32
      half8 af[4], bf[4];
      const int koff = kc * 32 + kg * 8;
#pragma unroll
      for (int m = 0; m < 4; ++m)
        af[m] = *(const half8*)&la[(wr * 64 + m * 16 + lr) * 200 + koff];
#pragma unroll
      for (int n = 0; n < 4; ++n)
        bf[n] = *(const half8*)&lb[(wc * 64 + n * 16 + lr) * 200 + koff];
#pragma unroll
      for (int m = 0; m < 4; ++m)
#pragma unroll
        for (int n = 0; n < 4; ++n)
          acc[m][n] = __builtin_amdgcn_mfma_f32_16x16x32_f16(af[m], bf[n], acc[m][n], 0, 0, 0);
    }

    const int rb = bm * 128 + wr * 64;
    const int cb = bn * 128 + wc * 64;
#pragma unroll
    for (int m = 0; m < 4; ++m)
#pragma unroll
      for (int n = 0; n < 4; ++n) {
        const int r0 = rb + m * 16 + kg * 4;  // C/D: col=lane&15, row=(lane>>4)*4+e
        const int c0 = cb + n * 16 + lr;
#pragma unroll
        for (int e = 0; e < 4; ++e)
          Gh[(size_t)(r0 + e) * 2048 + c0] = (_Float16)acc[m][n][e];  // R1 shape, 2B
      }
  }
  gridbar(cnts + 16, 256);

  // ---- phase 2: rows b*8..b*8+7, all interleaved in registers ----
  {
    half8 vr[8];
#pragma unroll
    for (int rr = 0; rr < 8; ++rr)  // 8 independent 16B loads in flight
      vr[rr] = *(const half8*)&Gh[(size_t)(b * 8 + rr) * 2048 + t * 8];

    const int base = (t * 8) & 1023;
    const int4 la0 = *(const int4*)&labels[base];
    const int4 la1 = *(const int4*)&labels[base + 4];
    const int labs[8] = {la0.x, la0.y, la0.z, la0.w, la1.x, la1.y, la1.z, la1.w};

    float ssA[8], mxA[8];
#pragma unroll
    for (int rr = 0; rr < 8; ++rr) {
      float s = 0.f, m = -3.4e38f;
#pragma unroll
      for (int u = 0; u < 8; ++u) {
        float g = (float)vr[rr][u];
        s += g * g;
        m = fmaxf(m, g);
      }
      ssA[rr] = s; mxA[rr] = m;
    }
#pragma unroll
    for (int o = 32; o; o >>= 1)  // 16 interleaved butterfly chains
#pragma unroll
      for (int rr = 0; rr < 8; ++rr) {
        ssA[rr] += __shfl_xor(ssA[rr], o);
        mxA[rr] = fmaxf(mxA[rr], __shfl_xor(mxA[rr], o));
      }
    if (lane == 0)
#pragma unroll
      for (int rr = 0; rr < 8; ++rr) { cwS[rr][w] = ssA[rr]; cwM[rr][w] = mxA[rr]; }
    __syncthreads();

    float invn[8], Mst[8];
#pragma unroll
    for (int rr = 0; rr < 8; ++rr) {
      const float sst = cwS[rr][0] + cwS[rr][1] + cwS[rr][2] + cwS[rr][3];
      const float gmax = fmaxf(fmaxf(cwM[rr][0], cwM[rr][1]), fmaxf(cwM[rr][2], cwM[rr][3]));
      invn[rr] = 1.0f / fmaxf(sqrtf(sst), 1e-12f);
      Mst[rr] = xform(gmax * invn[rr]);
    }

    float esA[8], psA[8], cnA[8];
#pragma unroll
    for (int rr = 0; rr < 8; ++rr) {
      const int i = b * 8 + rr;
      const int mylab = labels[i & 1023];  // uniform -> s_load
      float es = 0.f, ps = 0.f, cn = 0.f;
#pragma unroll
      for (int u = 0; u < 8; ++u) {
        const int j = t * 8 + u;
        const float l = xform((float)vr[rr][u] * invn[rr]) - Mst[rr];
        if (j != i) {
          es += expf(l);
          if (labs[u] == mylab) { ps += l; cn += 1.f; }
        }
      }
      esA[rr] = es; psA[rr] = ps; cnA[rr] = cn;
    }
#pragma unroll
    for (int o = 32; o; o >>= 1)
#pragma unroll
      for (int rr = 0; rr < 8; ++rr) {
        esA[rr] += __shfl_xor(esA[rr], o);
        psA[rr] += __shfl_xor(psA[rr], o);
        cnA[rr] += __shfl_xor(cnA[rr], o);
      }
    if (lane == 0)
#pragma unroll
      for (int rr = 0; rr < 8; ++rr) { cwE[rr][w] = esA[rr]; cwP[rr][w] = psA[rr]; cwC[rr][w] = cnA[rr]; }
    __syncthreads();
    if (t == 0) {
      float lsum = 0.f;
#pragma unroll
      for (int rr = 0; rr < 8; ++rr) {
        const float E = cwE[rr][0] + cwE[rr][1] + cwE[rr][2] + cwE[rr][3];
        const float P = cwP[rr][0] + cwP[rr][1] + cwP[rr][2] + cwP[rr][3];
        const float C = cwC[rr][0] + cwC[rr][1] + cwC[rr][2] + cwC[rr][3];
        lsum += -(P / C - logf(E));
      }
      partials[b] = lsum;
      __threadfence();  // release partials[b] before announcing
      unsigned old = __hip_atomic_fetch_add(cnts + 32, 1u, __ATOMIC_RELAXED,
                                            __HIP_MEMORY_SCOPE_AGENT);
      lastf = (old == 255u);
    }
    __syncthreads();
  }

  // ---- phase 3: the last-arriving block reduces all partials -> out[0] ----
  if (lastf) {
    __threadfence();  // acquire: see every block's partials
    float s = partials[t];
#pragma unroll
    for (int o = 32; o; o >>= 1) s += __shfl_xor(s, o);
    if (lane == 0) r4[w] = s;
    __syncthreads();
    if (t == 0) out[0] = (r4[0] + r4[1] + r4[2] + r4[3]) * (1.0f / 2048.0f);
  }
}

extern "C" void kernel_launch(void* const* d_in, const int* in_sizes, int n_in,
                              void* d_out, int out_size, void* d_ws, size_t ws_size,
                              hipStream_t stream) {
  const float* feats = (const float*)d_in[0];
  const int* labels = (const int*)d_in[1];
  // d_in[2]/d_in[3] (fc_w/fc_b) are provably dead: atten == 1.0 exactly

  char* ws = (char*)d_ws;
  unsigned* cnts = (unsigned*)ws;               // 3 counters @ byte 0 / 64 / 128
  float* partials = (float*)(ws + 256);         // 256 * 4 B
  _Float16* cfn = (_Float16*)(ws + 4096);       // 2048*192*2  = 768 KiB
  _Float16* Gh  = (_Float16*)(ws + (1 << 20));  // 2048*2048*2 = 8 MiB

  hipMemsetAsync(ws, 0, 256, stream);  // zero barrier counters (poison/replay-proof)
  k_fused<<<256, 256, 0, stream>>>(feats, labels, cnts, partials, cfn, Gh,
                                   (float*)d_out);
}

// Round 5
// 62.546 us; speedup vs baseline: 1.6439x; 1.6439x over previous
//
#include <hip/hip_runtime.h>

typedef __attribute__((ext_vector_type(8))) _Float16 half8;
typedef __attribute__((ext_vector_type(4))) float f32x4;

// ---- constants from the reference ----
#define COS_M 0.98006657784124163f
#define SIN_M 0.19866933079506122f
#define TH_C  (-0.98006657784124163f)
#define MM_C  0.039733866159012244f
#define S_OVER_TEMP (10.0f / 0.07f)

// monotone-in-c transform: c -> S*phi(c)/TEMP (loss invariant to stabilizer
// choice, so xform(rowmax * invn) works as the log-sum-exp stabilizer)
__device__ inline float xform(float c) {
  float s2 = fmaxf(1.0f - c * c, 0.0f);
  float sn = sqrtf(s2);
  float phi = c * COS_M - sn * SIN_M;
  float out = (c - TH_C > 0.0f) ? phi : (c - MM_C);
  return out * S_OVER_TEMP;
}

// ---------------- K1: cf = l2norm rows of concat(views) -> f16 ----------------
__global__ __launch_bounds__(64) void k_normalize(const float* __restrict__ feats,
                                                  _Float16* __restrict__ cfn) {
  const int i = blockIdx.x;  // row in [0, 2048)
  const int b = i & 1023, v = i >> 10;
  const float* src = feats + ((size_t)b * 2 + v) * 192;
  const int t = threadIdx.x;
  float x0 = src[t], x1 = src[t + 64], x2 = src[t + 128];
  float ss = x0 * x0 + x1 * x1 + x2 * x2;
#pragma unroll
  for (int o = 32; o; o >>= 1) ss += __shfl_down(ss, o);
  ss = __shfl(ss, 0);
  float inv = 1.0f / fmaxf(sqrtf(ss), 1e-12f);
  _Float16* dst = cfn + (size_t)i * 192;
  dst[t]       = (_Float16)(x0 * inv);
  dst[t + 64]  = (_Float16)(x1 * inv);
  dst[t + 128] = (_Float16)(x2 * inv);
}

// ---------------- K2: G = cfn * cfn^T -> f16, R1-shape coalesced store --------
// 128x128 tile per block, 4 waves (2x2), each wave 64x64 = 4x4 frags of 16x16.
__global__ __launch_bounds__(256) void k_gemm(const _Float16* __restrict__ cfn,
                                              _Float16* __restrict__ Gh) {
  __shared__ alignas(16) _Float16 la[128 * 200];  // stride 200: 2-way alias = free
  __shared__ alignas(16) _Float16 lb[128 * 200];
  const int bm = blockIdx.x, bn = blockIdx.y;
  const uint4* srcA = (const uint4*)(cfn + (size_t)bm * 128 * 192);
  const uint4* srcB = (const uint4*)(cfn + (size_t)bn * 128 * 192);
  for (int idx = threadIdx.x; idx < 3072; idx += 256) {  // 128 rows * 24 uint4/row
    int r = idx / 24, c = idx - r * 24;
    *(uint4*)&la[r * 200 + c * 8] = srcA[idx];
    *(uint4*)&lb[r * 200 + c * 8] = srcB[idx];
  }
  __syncthreads();

  const int lane = threadIdx.x & 63;
  const int w = threadIdx.x >> 6;
  const int wr = w >> 1, wc = w & 1;  // 2x2 wave grid, 64x64 each
  const int lr = lane & 15, kg = lane >> 4;

  f32x4 acc[4][4];
#pragma unroll
  for (int m = 0; m < 4; ++m)
#pragma unroll
    for (int n = 0; n < 4; ++n) acc[m][n] = (f32x4){0.f, 0.f, 0.f, 0.f};

#pragma unroll
  for (int kc = 0; kc < 6; ++kc) {  // K = 192 = 6 * 32
    half8 af[4], bf[4];
    const int koff = kc * 32 + kg * 8;
#pragma unroll
    for (int m = 0; m < 4; ++m)
      af[m] = *(const half8*)&la[(wr * 64 + m * 16 + lr) * 200 + koff];
#pragma unroll
    for (int n = 0; n < 4; ++n)
      bf[n] = *(const half8*)&lb[(wc * 64 + n * 16 + lr) * 200 + koff];
#pragma unroll
    for (int m = 0; m < 4; ++m)
#pragma unroll
      for (int n = 0; n < 4; ++n)
        acc[m][n] = __builtin_amdgcn_mfma_f32_16x16x32_f16(af[m], bf[n], acc[m][n], 0, 0, 0);
  }

  const int rb = bm * 128 + wr * 64;
  const int cb = bn * 128 + wc * 64;
#pragma unroll
  for (int m = 0; m < 4; ++m)
#pragma unroll
    for (int n = 0; n < 4; ++n) {
      const int r0 = rb + m * 16 + kg * 4;  // C/D: col=lane&15, row=(lane>>4)*4+e
      const int c0 = cb + n * 16 + lr;
#pragma unroll
      for (int e = 0; e < 4; ++e)  // 16 lanes -> contiguous 32B segment (validated R4)
        Gh[(size_t)(r0 + e) * 2048 + c0] = (_Float16)acc[m][n][e];
    }
}

// ---------------- K3: per-row loss + fence/ticket final reduction -------------
__global__ __launch_bounds__(256) void k_rowloss(const _Float16* __restrict__ Gh,
                                                 const int* __restrict__ labels,
                                                 float* __restrict__ partials,
                                                 unsigned* __restrict__ ticket,
                                                 float* __restrict__ out) {
  const int i = blockIdx.x;
  const int t = threadIdx.x;
  const int lane = t & 63, w = t >> 6;
  __shared__ float s4[4], m4[4], e4[4], p4[4], c4[4], r4[4];
  __shared__ int lastf;

  half8 v = *(const half8*)&Gh[(size_t)i * 2048 + t * 8];
  float gv[8];
#pragma unroll
  for (int u = 0; u < 8; ++u) gv[u] = (float)v[u];

  float ss = 0.f, mx = -3.4e38f;
#pragma unroll
  for (int u = 0; u < 8; ++u) { ss += gv[u] * gv[u]; mx = fmaxf(mx, gv[u]); }
#pragma unroll
  for (int o = 32; o; o >>= 1) {
    ss += __shfl_down(ss, o);
    mx = fmaxf(mx, __shfl_down(mx, o));
  }
  if (lane == 0) { s4[w] = ss; m4[w] = mx; }
  __syncthreads();
  const float sst = s4[0] + s4[1] + s4[2] + s4[3];
  const float gmax = fmaxf(fmaxf(m4[0], m4[1]), fmaxf(m4[2], m4[3]));
  const float invn = 1.0f / fmaxf(sqrtf(sst), 1e-12f);
  const float Mst = xform(gmax * invn);  // stabilizer (loss-invariant choice)

  const int base = (t * 8) & 1023;
  const int4 la0 = *(const int4*)&labels[base];
  const int4 la1 = *(const int4*)&labels[base + 4];
  const int labs[8] = {la0.x, la0.y, la0.z, la0.w, la1.x, la1.y, la1.z, la1.w};
  const int mylab = labels[i & 1023];

  float es = 0.f, ps = 0.f, cn = 0.f;
#pragma unroll
  for (int u = 0; u < 8; ++u) {
    const int j = t * 8 + u;
    const float l = xform(gv[u] * invn) - Mst;
    if (j != i) {
      es += expf(l);
      if (labs[u] == mylab) { ps += l; cn += 1.f; }
    }
  }
#pragma unroll
  for (int o = 32; o; o >>= 1) {
    es += __shfl_down(es, o);
    ps += __shfl_down(ps, o);
    cn += __shfl_down(cn, o);
  }
  if (lane == 0) { e4[w] = es; p4[w] = ps; c4[w] = cn; }
  __syncthreads();
  if (t == 0) {
    const float E = e4[0] + e4[1] + e4[2] + e4[3];
    const float P = p4[0] + p4[1] + p4[2] + p4[3];
    const float C = c4[0] + c4[1] + c4[2] + c4[3];
    partials[i] = -(P / C - logf(E));
    __threadfence();  // release partials[i] before taking the ticket
    unsigned old = __hip_atomic_fetch_add(ticket, 1u, __ATOMIC_RELAXED,
                                          __HIP_MEMORY_SCOPE_AGENT);
    lastf = (old == 2047u);  // last block to finish does the final reduce
  }
  __syncthreads();

  if (lastf) {  // no spinning: all 2047 other partials are already released
    __threadfence();  // acquire side
    float s = 0.f;
#pragma unroll
    for (int q = 0; q < 8; ++q) s += partials[t + q * 256];
#pragma unroll
    for (int o = 32; o; o >>= 1) s += __shfl_down(s, o);
    if (lane == 0) r4[w] = s;
    __syncthreads();
    if (t == 0) out[0] = (r4[0] + r4[1] + r4[2] + r4[3]) * (1.0f / 2048.0f);
  }
}

extern "C" void kernel_launch(void* const* d_in, const int* in_sizes, int n_in,
                              void* d_out, int out_size, void* d_ws, size_t ws_size,
                              hipStream_t stream) {
  const float* feats = (const float*)d_in[0];
  const int* labels = (const int*)d_in[1];
  // d_in[2]/d_in[3] (fc_w/fc_b) are provably dead: atten == 1.0 exactly

  char* ws = (char*)d_ws;
  unsigned* ticket = (unsigned*)ws;             // @0, zeroed each call
  float* partials  = (float*)(ws + 256);        // 2048 * 4 B
  _Float16* cfn    = (_Float16*)(ws + 16384);   // 2048*192*2  = 768 KiB
  _Float16* Gh     = (_Float16*)(ws + (1 << 20));  // 2048*2048*2 = 8 MiB

  hipMemsetAsync(ws, 0, 64, stream);  // zero ticket (graph-capturable)
  k_normalize<<<2048, 64, 0, stream>>>(feats, cfn);
  dim3 g2(16, 16);
  k_gemm<<<g2, 256, 0, stream>>>(cfn, Gh);
  k_rowloss<<<2048, 256, 0, stream>>>(Gh, labels, partials, ticket, (float*)d_out);
}

// Round 6
// 31.552 us; speedup vs baseline: 3.2586x; 1.9823x over previous
//
#include <hip/hip_runtime.h>

typedef __attribute__((ext_vector_type(8))) _Float16 half8;
typedef __attribute__((ext_vector_type(4))) float f32x4;

// ---- constants from the reference ----
#define COS_M 0.98006657784124163f
#define SIN_M 0.19866933079506122f
#define TH_C  (-0.98006657784124163f)
#define MM_C  0.039733866159012244f
#define S_OVER_TEMP (10.0f / 0.07f)

// monotone-in-c transform: c -> S*phi(c)/TEMP (loss invariant to stabilizer
// choice, so xform(rowmax * invn) works as the log-sum-exp stabilizer)
__device__ inline float xform(float c) {
  float s2 = fmaxf(1.0f - c * c, 0.0f);
  float sn = sqrtf(s2);
  float phi = c * COS_M - sn * SIN_M;
  float out = (c - TH_C > 0.0f) ? phi : (c - MM_C);
  return out * S_OVER_TEMP;
}

// ---------------- K1: cf = l2norm rows of concat(views) -> f16 ----------------
__global__ __launch_bounds__(64) void k_normalize(const float* __restrict__ feats,
                                                  _Float16* __restrict__ cfn) {
  const int i = blockIdx.x;  // row in [0, 2048)
  const int b = i & 1023, v = i >> 10;
  const float* src = feats + ((size_t)b * 2 + v) * 192;
  const int t = threadIdx.x;
  float x0 = src[t], x1 = src[t + 64], x2 = src[t + 128];
  float ss = x0 * x0 + x1 * x1 + x2 * x2;
#pragma unroll
  for (int o = 32; o; o >>= 1) ss += __shfl_down(ss, o);
  ss = __shfl(ss, 0);
  float inv = 1.0f / fmaxf(sqrtf(ss), 1e-12f);
  _Float16* dst = cfn + (size_t)i * 192;
  dst[t]       = (_Float16)(x0 * inv);
  dst[t + 64]  = (_Float16)(x1 * inv);
  dst[t + 128] = (_Float16)(x2 * inv);
}

// ---------------- K2: G = cfn * cfn^T -> f16, R1-shape coalesced store --------
// 128x128 tile per block, 4 waves (2x2), each wave 64x64 = 4x4 frags of 16x16.
__global__ __launch_bounds__(256) void k_gemm(const _Float16* __restrict__ cfn,
                                              _Float16* __restrict__ Gh) {
  __shared__ alignas(16) _Float16 la[128 * 200];  // stride 200: 2-way alias = free
  __shared__ alignas(16) _Float16 lb[128 * 200];
  const int bm = blockIdx.x, bn = blockIdx.y;
  const uint4* srcA = (const uint4*)(cfn + (size_t)bm * 128 * 192);
  const uint4* srcB = (const uint4*)(cfn + (size_t)bn * 128 * 192);
  for (int idx = threadIdx.x; idx < 3072; idx += 256) {  // 128 rows * 24 uint4/row
    int r = idx / 24, c = idx - r * 24;
    *(uint4*)&la[r * 200 + c * 8] = srcA[idx];
    *(uint4*)&lb[r * 200 + c * 8] = srcB[idx];
  }
  __syncthreads();

  const int lane = threadIdx.x & 63;
  const int w = threadIdx.x >> 6;
  const int wr = w >> 1, wc = w & 1;  // 2x2 wave grid, 64x64 each
  const int lr = lane & 15, kg = lane >> 4;

  f32x4 acc[4][4];
#pragma unroll
  for (int m = 0; m < 4; ++m)
#pragma unroll
    for (int n = 0; n < 4; ++n) acc[m][n] = (f32x4){0.f, 0.f, 0.f, 0.f};

#pragma unroll
  for (int kc = 0; kc < 6; ++kc) {  // K = 192 = 6 * 32
    half8 af[4], bf[4];
    const int koff = kc * 32 + kg * 8;
#pragma unroll
    for (int m = 0; m < 4; ++m)
      af[m] = *(const half8*)&la[(wr * 64 + m * 16 + lr) * 200 + koff];
#pragma unroll
    for (int n = 0; n < 4; ++n)
      bf[n] = *(const half8*)&lb[(wc * 64 + n * 16 + lr) * 200 + koff];
#pragma unroll
    for (int m = 0; m < 4; ++m)
#pragma unroll
      for (int n = 0; n < 4; ++n)
        acc[m][n] = __builtin_amdgcn_mfma_f32_16x16x32_f16(af[m], bf[n], acc[m][n], 0, 0, 0);
  }

  const int rb = bm * 128 + wr * 64;
  const int cb = bn * 128 + wc * 64;
#pragma unroll
  for (int m = 0; m < 4; ++m)
#pragma unroll
    for (int n = 0; n < 4; ++n) {
      const int r0 = rb + m * 16 + kg * 4;  // C/D: col=lane&15, row=(lane>>4)*4+e
      const int c0 = cb + n * 16 + lr;
#pragma unroll
      for (int e = 0; e < 4; ++e)  // 16 lanes -> contiguous 32B segment (validated R4/R5)
        Gh[(size_t)(r0 + e) * 2048 + c0] = (_Float16)acc[m][n][e];
    }
}

// ---------------- K3: one wave per row, zero sync, no atomics -----------------
// lane l, pass p handles j = 512p + 8l + u (u=0..7). attlabels tile with period
// 1024 -> passes 0,2 and 1,3 share label slices: only 2 slices loaded.
__global__ __launch_bounds__(64) void k_rowloss(const _Float16* __restrict__ Gh,
                                                const int* __restrict__ labels,
                                                float* __restrict__ lossv) {
  const int i = blockIdx.x;
  const int l = threadIdx.x;
  const _Float16* row = Gh + (size_t)i * 2048;

  half8 v[4];
#pragma unroll
  for (int p = 0; p < 4; ++p)  // 4 independent 16B loads in flight
    v[p] = *(const half8*)&row[512 * p + 8 * l];

  float gv[4][8];
#pragma unroll
  for (int p = 0; p < 4; ++p)
#pragma unroll
    for (int u = 0; u < 8; ++u) gv[p][u] = (float)v[p][u];

  float ss = 0.f, mx = -3.4e38f;
#pragma unroll
  for (int p = 0; p < 4; ++p)
#pragma unroll
    for (int u = 0; u < 8; ++u) { ss += gv[p][u] * gv[p][u]; mx = fmaxf(mx, gv[p][u]); }
#pragma unroll
  for (int o = 32; o; o >>= 1) {  // wave-wide butterfly, no LDS
    ss += __shfl_xor(ss, o);
    mx = fmaxf(mx, __shfl_xor(mx, o));
  }
  const float invn = 1.0f / fmaxf(sqrtf(ss), 1e-12f);
  const float Mst = xform(mx * invn);  // stabilizer (loss-invariant choice)

  const int4 a0 = *(const int4*)&labels[8 * l];
  const int4 a1 = *(const int4*)&labels[8 * l + 4];
  const int4 b0 = *(const int4*)&labels[512 + 8 * l];
  const int4 b1 = *(const int4*)&labels[512 + 8 * l + 4];
  const int labs[2][8] = {{a0.x, a0.y, a0.z, a0.w, a1.x, a1.y, a1.z, a1.w},
                          {b0.x, b0.y, b0.z, b0.w, b1.x, b1.y, b1.z, b1.w}};
  const int mylab = labels[i & 1023];  // wave-uniform -> scalar load

  float es = 0.f, ps = 0.f, cn = 0.f;
#pragma unroll
  for (int p = 0; p < 4; ++p)
#pragma unroll
    for (int u = 0; u < 8; ++u) {
      const int j = 512 * p + 8 * l + u;
      const float lg = xform(gv[p][u] * invn) - Mst;
      if (j != i) {
        es += expf(lg);
        if (labs[p & 1][u] == mylab) { ps += lg; cn += 1.f; }
      }
    }
#pragma unroll
  for (int o = 32; o; o >>= 1) {
    es += __shfl_xor(es, o);
    ps += __shfl_xor(ps, o);
    cn += __shfl_xor(cn, o);
  }
  if (l == 0) lossv[i] = -(ps / cn - logf(es));
}

// ---------------- K4: mean over 2048 rows -> scalar ----------------
__global__ __launch_bounds__(256) void k_final(const float* __restrict__ lossv,
                                               float* __restrict__ out) {
  const int t = threadIdx.x;
  float s = 0.f;
  for (int j = t; j < 2048; j += 256) s += lossv[j];
#pragma unroll
  for (int o = 32; o; o >>= 1) s += __shfl_down(s, o);
  __shared__ float r4[4];
  if ((t & 63) == 0) r4[t >> 6] = s;
  __syncthreads();
  if (t == 0) out[0] = (r4[0] + r4[1] + r4[2] + r4[3]) * (1.0f / 2048.0f);
}

extern "C" void kernel_launch(void* const* d_in, const int* in_sizes, int n_in,
                              void* d_out, int out_size, void* d_ws, size_t ws_size,
                              hipStream_t stream) {
  const float* feats = (const float*)d_in[0];
  const int* labels = (const int*)d_in[1];
  // d_in[2]/d_in[3] (fc_w/fc_b) are provably dead: atten == 1.0 exactly

  char* ws = (char*)d_ws;
  float* lossv  = (float*)ws;                   // 2048 * 4 B
  _Float16* cfn = (_Float16*)(ws + 16384);      // 2048*192*2  = 768 KiB
  _Float16* Gh  = (_Float16*)(ws + (1 << 20));  // 2048*2048*2 = 8 MiB

  k_normalize<<<2048, 64, 0, stream>>>(feats, cfn);
  dim3 g2(16, 16);
  k_gemm<<<g2, 256, 0, stream>>>(cfn, Gh);
  k_rowloss<<<2048, 64, 0, stream>>>(Gh, labels, lossv);
  k_final<<<1, 256, 0, stream>>>(lossv, (float*)d_out);
}

// Round 7
// 29.128 us; speedup vs baseline: 3.5298x; 1.0832x over previous
//
#include <hip/hip_runtime.h>

typedef __attribute__((ext_vector_type(8))) _Float16 half8;
typedef __attribute__((ext_vector_type(4))) float f32x4;

// ---- constants from the reference ----
#define COS_M 0.98006657784124163f
#define SIN_M 0.19866933079506122f
#define TH_C  (-0.98006657784124163f)
#define MM_C  0.039733866159012244f
#define S_OVER_TEMP (10.0f / 0.07f)

// monotone-in-c transform: c -> S*phi(c)/TEMP (loss invariant to stabilizer
// choice, so xform(rowmax * invn) works as the log-sum-exp stabilizer)
__device__ inline float xform(float c) {
  float s2 = fmaxf(1.0f - c * c, 0.0f);
  float sn = sqrtf(s2);
  float phi = c * COS_M - sn * SIN_M;
  float out = (c - TH_C > 0.0f) ? phi : (c - MM_C);
  return out * S_OVER_TEMP;
}

// ---- K2': fused normalize + G = norm(F)*norm(F)^T -> f16 --------------------
// G[i,j] = (f_i . f_j) * invn_i * invn_j : stage RAW features f32->f16 into
// LDS, accumulate row sumsq during staging (free), scale in the epilogue.
// 128x128 tile per block, 4 waves (2x2), each wave 64x64 = 4x4 frags of 16x16.
__global__ __launch_bounds__(256) void k_gemm_norm(const float* __restrict__ feats,
                                                   _Float16* __restrict__ Gh) {
  __shared__ alignas(16) _Float16 la[128 * 200];  // stride 200: 2-way alias = free
  __shared__ alignas(16) _Float16 lb[128 * 200];
  __shared__ float rsA[128], rsBs[128];
  const int bm = blockIdx.x, bn = blockIdx.y;
  const int t = threadIdx.x;
  const bool diag = (bn == bm);

  // stage one 128-row tile: cast f32->f16 into lds, rowwise sumsq -> rs[]
  auto stage = [&](int bt, _Float16* lds, float* rs) {
    const int rr = t >> 1, h = t & 1;  // 2 threads per row, 96 floats each
    const int r = bt * 128 + rr;
    const float4* s4 =
        (const float4*)(feats + (size_t)((r & 1023) * 2 + (r >> 10)) * 192 + h * 96);
    float ss = 0.f;
    _Float16* dst = lds + rr * 200 + h * 96;
#pragma unroll
    for (int q = 0; q < 12; ++q) {
      float4 va = s4[2 * q], vb = s4[2 * q + 1];
      ss += va.x * va.x + va.y * va.y + va.z * va.z + va.w * va.w;
      ss += vb.x * vb.x + vb.y * vb.y + vb.z * vb.z + vb.w * vb.w;
      half8 o = {(_Float16)va.x, (_Float16)va.y, (_Float16)va.z, (_Float16)va.w,
                 (_Float16)vb.x, (_Float16)vb.y, (_Float16)vb.z, (_Float16)vb.w};
      *(half8*)(dst + q * 8) = o;
    }
    ss += __shfl_xor(ss, 1);  // pair (2k,2k+1): full-row sumsq
    if (h == 0) rs[rr] = rsqrtf(fmaxf(ss, 1e-24f));
  };
  stage(bm, la, rsA);
  if (!diag) stage(bn, lb, rsBs);
  __syncthreads();
  const _Float16* Bp = diag ? la : lb;
  const float* rsB = diag ? rsA : rsBs;

  const int lane = t & 63;
  const int w = t >> 6;
  const int wr = w >> 1, wc = w & 1;  // 2x2 wave grid, 64x64 each
  const int lr = lane & 15, kg = lane >> 4;

  f32x4 acc[4][4];
#pragma unroll
  for (int m = 0; m < 4; ++m)
#pragma unroll
    for (int n = 0; n < 4; ++n) acc[m][n] = (f32x4){0.f, 0.f, 0.f, 0.f};

#pragma unroll
  for (int kc = 0; kc < 6; ++kc) {  // K = 192 = 6 * 32
    half8 af[4], bf[4];
    const int koff = kc * 32 + kg * 8;
#pragma unroll
    for (int m = 0; m < 4; ++m)
      af[m] = *(const half8*)&la[(wr * 64 + m * 16 + lr) * 200 + koff];
#pragma unroll
    for (int n = 0; n < 4; ++n)
      bf[n] = *(const half8*)&Bp[(wc * 64 + n * 16 + lr) * 200 + koff];
#pragma unroll
    for (int m = 0; m < 4; ++m)
#pragma unroll
      for (int n = 0; n < 4; ++n)
        acc[m][n] = __builtin_amdgcn_mfma_f32_16x16x32_f16(af[m], bf[n], acc[m][n], 0, 0, 0);
  }

  const int rb = bm * 128 + wr * 64;
  const int cb = bn * 128 + wc * 64;
#pragma unroll
  for (int m = 0; m < 4; ++m)
#pragma unroll
    for (int n = 0; n < 4; ++n) {
      const int r0 = rb + m * 16 + kg * 4;  // C/D: col=lane&15, row=(lane>>4)*4+e
      const int c0 = cb + n * 16 + lr;
      const float sb = rsB[wc * 64 + n * 16 + lr];
#pragma unroll
      for (int e = 0; e < 4; ++e) {  // R1-shape store (validated R4/R5/R6)
        const float sa = rsA[wr * 64 + m * 16 + kg * 4 + e];
        Gh[(size_t)(r0 + e) * 2048 + c0] = (_Float16)(acc[m][n][e] * sa * sb);
      }
    }
}

// ---------------- K3: one wave per row, zero sync, no atomics -----------------
// lane l, pass p handles j = 512p + 8l + u (u=0..7). attlabels tile with period
// 1024 -> passes 0,2 and 1,3 share label slices: only 2 slices loaded.
__global__ __launch_bounds__(64) void k_rowloss(const _Float16* __restrict__ Gh,
                                                const int* __restrict__ labels,
                                                float* __restrict__ lossv) {
  const int i = blockIdx.x;
  const int l = threadIdx.x;
  const _Float16* row = Gh + (size_t)i * 2048;

  half8 v[4];
#pragma unroll
  for (int p = 0; p < 4; ++p)  // 4 independent 16B loads in flight
    v[p] = *(const half8*)&row[512 * p + 8 * l];

  float gv[4][8];
#pragma unroll
  for (int p = 0; p < 4; ++p)
#pragma unroll
    for (int u = 0; u < 8; ++u) gv[p][u] = (float)v[p][u];

  float ss = 0.f, mx = -3.4e38f;
#pragma unroll
  for (int p = 0; p < 4; ++p)
#pragma unroll
    for (int u = 0; u < 8; ++u) { ss += gv[p][u] * gv[p][u]; mx = fmaxf(mx, gv[p][u]); }
#pragma unroll
  for (int o = 32; o; o >>= 1) {  // wave-wide butterfly, no LDS
    ss += __shfl_xor(ss, o);
    mx = fmaxf(mx, __shfl_xor(mx, o));
  }
  const float invn = 1.0f / fmaxf(sqrtf(ss), 1e-12f);
  const float Mst = xform(mx * invn);  // stabilizer (loss-invariant choice)

  const int4 a0 = *(const int4*)&labels[8 * l];
  const int4 a1 = *(const int4*)&labels[8 * l + 4];
  const int4 b0 = *(const int4*)&labels[512 + 8 * l];
  const int4 b1 = *(const int4*)&labels[512 + 8 * l + 4];
  const int labs[2][8] = {{a0.x, a0.y, a0.z, a0.w, a1.x, a1.y, a1.z, a1.w},
                          {b0.x, b0.y, b0.z, b0.w, b1.x, b1.y, b1.z, b1.w}};
  const int mylab = labels[i & 1023];  // wave-uniform -> scalar load

  float es = 0.f, ps = 0.f, cn = 0.f;
#pragma unroll
  for (int p = 0; p < 4; ++p)
#pragma unroll
    for (int u = 0; u < 8; ++u) {
      const int j = 512 * p + 8 * l + u;
      const float lg = xform(gv[p][u] * invn) - Mst;
      if (j != i) {
        es += expf(lg);
        if (labs[p & 1][u] == mylab) { ps += lg; cn += 1.f; }
      }
    }
#pragma unroll
  for (int o = 32; o; o >>= 1) {
    es += __shfl_xor(es, o);
    ps += __shfl_xor(ps, o);
    cn += __shfl_xor(cn, o);
  }
  if (l == 0) lossv[i] = -(ps / cn - logf(es));
}

// ---------------- K4: mean over 2048 rows -> scalar ----------------
__global__ __launch_bounds__(256) void k_final(const float* __restrict__ lossv,
                                               float* __restrict__ out) {
  const int t = threadIdx.x;
  float s = 0.f;
  for (int j = t; j < 2048; j += 256) s += lossv[j];
#pragma unroll
  for (int o = 32; o; o >>= 1) s += __shfl_down(s, o);
  __shared__ float r4[4];
  if ((t & 63) == 0) r4[t >> 6] = s;
  __syncthreads();
  if (t == 0) out[0] = (r4[0] + r4[1] + r4[2] + r4[3]) * (1.0f / 2048.0f);
}

extern "C" void kernel_launch(void* const* d_in, const int* in_sizes, int n_in,
                              void* d_out, int out_size, void* d_ws, size_t ws_size,
                              hipStream_t stream) {
  const float* feats = (const float*)d_in[0];
  const int* labels = (const int*)d_in[1];
  // d_in[2]/d_in[3] (fc_w/fc_b) are provably dead: atten == 1.0 exactly

  char* ws = (char*)d_ws;
  float* lossv = (float*)ws;                    // 2048 * 4 B
  _Float16* Gh = (_Float16*)(ws + (1 << 20));   // 2048*2048*2 = 8 MiB

  dim3 g2(16, 16);
  k_gemm_norm<<<g2, 256, 0, stream>>>(feats, Gh);
  k_rowloss<<<2048, 64, 0, stream>>>(Gh, labels, lossv);
  k_final<<<1, 256, 0, stream>>>(lossv, (float*)d_out);
}